// Round 7
// baseline (33.896 us; speedup 1.0000x reference)
//
#include <hip/hip_runtime.h>
#include <math.h>

// Steerable CNP target prediction — separable-RBF factorization.
//
// out[t,c] = (sum_i Kx[t,i] * sum_j Ky[t,j] * FMc[j,i]) / (Sx[t]*Sy[t])
// Kx[t,i] = exp(-(xt0 - ax[i])^2 / (2 l^2)), channels 2,3 softplus'd first.
//
// Round 7: DS-broadcast-bound diagnosis. Replace per-FMA-quartet LDS
// broadcast reads of Ky (128 ds_read_b128/wave, ~16 useful B each) with
// register staging (8 lane-distinct ds_read_b32/wave) + v_readlane->SGPR
// broadcast feeding v_fmac_f32 v,s,v. DS pipe ~136 -> ~30 instrs/wave.
// TT=16 (512 blocks) halves L2 traffic. 8 waves = (j-quarter x ch-pair).

#define NA      128
#define TT      16    // targets per block -> 512 blocks
#define THREADS 512   // 8 waves: cp = wid&1, jq = wid>>1

__device__ __forceinline__ float rdlane(float v, int idx) {
    return __int_as_float(__builtin_amdgcn_readlane(__float_as_int(v), idx));
}

// ---------- pre-kernel: softplus(FM[2:4]) -> sp (2*128*128 floats) ----------
__global__ __launch_bounds__(256)
void softplus_pre(const float* __restrict__ fm, float* __restrict__ sp)
{
    const int idx = blockIdx.x * 256 + threadIdx.x;          // float4 index
    const int n4  = 2 * NA * NA / 4;                         // 8192
    if (idx >= n4) return;
    float4 v = reinterpret_cast<const float4*>(fm + 2 * NA * NA)[idx];
    v.x = (v.x > 15.0f) ? v.x : log1pf(__expf(v.x));
    v.y = (v.y > 15.0f) ? v.y : log1pf(__expf(v.y));
    v.z = (v.z > 15.0f) ? v.z : log1pf(__expf(v.z));
    v.w = (v.w > 15.0f) ? v.w : log1pf(__expf(v.w));
    reinterpret_cast<float4*>(sp)[idx] = v;
}

// ---------- main kernel ----------
__global__ __launch_bounds__(THREADS)
void cnp_main(const float* __restrict__ fm,    // [4][NA][NA]
              const float* __restrict__ sp,    // [2][NA][NA] softplus'd c2,c3
              const float* __restrict__ grid,  // [NA*NA][2]
              const float* __restrict__ xt,    // [T][2]
              const float* __restrict__ lsp,   // [1]
              float* __restrict__ out,         // means [T][2] then sigmas [T][2]
              int n_target, int use_sp)
{
    __shared__ __attribute__((aligned(16))) float Kx[TT * NA];
    __shared__ __attribute__((aligned(16))) float Ky[TT * NA];
    __shared__ float red[4][4][TT];   // (channel, j-quarter, target)
    __shared__ float psx[TT][2];      // Sx partials per (t, j-half)
    __shared__ float psy[TT][2];

    const int tid  = threadIdx.x;
    const int wid  = tid >> 6;        // 0..7
    const int cp   = wid & 1;         // channel pair: 0 -> {0,1}, 1 -> {2,3}
    const int jq   = wid >> 1;        // j-quarter 0..3 (32 rows each)
    const int lane = tid & 63;
    const int ch   = lane >> 5;       // channel within pair
    const int ig   = lane & 31;       // i-group
    const int i4   = ig * 4;          // this thread's 4 i-columns
    const int c    = cp * 2 + ch;
    const int t0   = blockIdx.x * TT;

    const float l      = lsp[0];
    const float inv2l2 = 0.5f / (l * l);

    // ---- phase 0: kernel rows into LDS + Sx/Sy partials via wave reduce ----
    // grid[g] = (ax[g>>7], ax[g&127])  =>  ax[j] = grid[j*2+1]
    // per (wave, s): all 64 lanes share t = 4s + (wid>>1), j-half = wid&1
#pragma unroll
    for (int s = 0; s < 4; ++s) {
        const int k = s * THREADS + tid;     // 0..2047
        const int t = k >> 7;
        const int j = k & 127;
        int tg = t0 + t; if (tg >= n_target) tg = n_target - 1;
        const float ax = grid[j * 2 + 1];
        const float dx = xt[tg * 2 + 0] - ax;
        const float dy = xt[tg * 2 + 1] - ax;
        const float kxv = __expf(-dx * dx * inv2l2);
        const float kyv = __expf(-dy * dy * inv2l2);
        Kx[k] = kxv;
        Ky[k] = kyv;
        float sx = kxv, sy = kyv;
        sx += __shfl_xor(sx, 1);  sy += __shfl_xor(sy, 1);
        sx += __shfl_xor(sx, 2);  sy += __shfl_xor(sy, 2);
        sx += __shfl_xor(sx, 4);  sy += __shfl_xor(sy, 4);
        sx += __shfl_xor(sx, 8);  sy += __shfl_xor(sy, 8);
        sx += __shfl_xor(sx, 16); sy += __shfl_xor(sy, 16);
        sx += __shfl_xor(sx, 32); sy += __shfl_xor(sy, 32);
        if (lane == 0) { psx[t][wid & 1] = sx; psy[t][wid & 1] = sy; }
    }
    __syncthreads();

    // ---- stage this wave's Ky window (16 t x 32 j) into 8 VGPRs ----
    // r{q}: lane L holds Ky[(2q + (L>>5))*NA + j0 + (L&31)]
    const int j0 = jq * 32;
    const float r0 = Ky[(0  + ch) * NA + j0 + ig];
    const float r1 = Ky[(2  + ch) * NA + j0 + ig];
    const float r2 = Ky[(4  + ch) * NA + j0 + ig];
    const float r3 = Ky[(6  + ch) * NA + j0 + ig];
    const float r4 = Ky[(8  + ch) * NA + j0 + ig];
    const float r5 = Ky[(10 + ch) * NA + j0 + ig];
    const float r6 = Ky[(12 + ch) * NA + j0 + ig];
    const float r7 = Ky[(14 + ch) * NA + j0 + ig];

    // ---- phase 1: acc[t] += Ky[t,j] * FMc[j, i4..i4+3] over my 32 j ----
    const float* srcc = (cp == 0) ? (fm + c * NA * NA)
                      : (use_sp ? (sp + (c - 2) * NA * NA) : (fm + c * NA * NA));
    const bool do_sp_inline = (!use_sp) && (cp == 1);
    const float* bp = srcc + j0 * NA + i4;

    float4 a0, a1, a2, a3, a4, a5, a6, a7, a8, a9, a10, a11, a12, a13, a14, a15;
    a0 = a1 = a2 = a3 = a4 = a5 = a6 = a7 = make_float4(0.f, 0.f, 0.f, 0.f);
    a8 = a9 = a10 = a11 = a12 = a13 = a14 = a15 = make_float4(0.f, 0.f, 0.f, 0.f);

#define FMA4(A, S, F)                                                          \
    A.x = fmaf((S), F.x, A.x); A.y = fmaf((S), F.y, A.y);                      \
    A.z = fmaf((S), F.z, A.z); A.w = fmaf((S), F.w, A.w);

#define PAIR(R, AE, AO, F, JJ)                                                 \
    {                                                                          \
        const float ke = rdlane(R, (JJ));                                      \
        const float ko = rdlane(R, (JJ) + 32);                                 \
        FMA4(AE, ke, F) FMA4(AO, ko, F)                                        \
    }

#pragma unroll 2
    for (int jj = 0; jj < 32; ++jj) {
        float4 f = *reinterpret_cast<const float4*>(bp + jj * NA);
        if (do_sp_inline) {   // fallback only if ws too small (dead in practice)
            f.x = (f.x > 15.0f) ? f.x : log1pf(__expf(f.x));
            f.y = (f.y > 15.0f) ? f.y : log1pf(__expf(f.y));
            f.z = (f.z > 15.0f) ? f.z : log1pf(__expf(f.z));
            f.w = (f.w > 15.0f) ? f.w : log1pf(__expf(f.w));
        }
        PAIR(r0, a0,  a1,  f, jj) PAIR(r1, a2,  a3,  f, jj)
        PAIR(r2, a4,  a5,  f, jj) PAIR(r3, a6,  a7,  f, jj)
        PAIR(r4, a8,  a9,  f, jj) PAIR(r5, a10, a11, f, jj)
        PAIR(r6, a12, a13, f, jj) PAIR(r7, a14, a15, f, jj)
    }
#undef PAIR
#undef FMA4

    // ---- phase 2: apply Kx, reduce over 32 i-lanes -> red[c][jq][t] ----
    // shfl strides <= 16 stay within each 32-lane channel group
#define RED(T, A)                                                              \
    {                                                                          \
        const float4 kx4 = *reinterpret_cast<const float4*>(&Kx[(T) * NA + i4]); \
        float w = fmaf(kx4.x, A.x, fmaf(kx4.y, A.y, fmaf(kx4.z, A.z, kx4.w * A.w))); \
        w += __shfl_xor(w, 1);  w += __shfl_xor(w, 2);  w += __shfl_xor(w, 4); \
        w += __shfl_xor(w, 8);  w += __shfl_xor(w, 16);                        \
        if (ig == 0) red[c][jq][(T)] = w;                                      \
    }
    RED(0,  a0)  RED(1,  a1)  RED(2,  a2)  RED(3,  a3)
    RED(4,  a4)  RED(5,  a5)  RED(6,  a6)  RED(7,  a7)
    RED(8,  a8)  RED(9,  a9)  RED(10, a10) RED(11, a11)
    RED(12, a12) RED(13, a13) RED(14, a14) RED(15, a15)
#undef RED
    __syncthreads();

    // ---- phase 3: combine j-quarters, normalize, write (64 outputs) ----
    if (tid < 4 * TT) {
        const int t  = tid & (TT - 1);
        const int cc = tid >> 4;            // requires TT == 16
        const int tg = t0 + t;
        if (tg < n_target) {
            const float numer = red[cc][0][t] + red[cc][1][t]
                              + red[cc][2][t] + red[cc][3][t];
            const float Sx = psx[t][0] + psx[t][1];
            const float Sy = psy[t][0] + psy[t][1];
            const float val = numer / (Sx * Sy);
            if (cc < 2) out[tg * 2 + cc] = val;                        // means
            else        out[n_target * 2 + tg * 2 + (cc - 2)] = val;   // sigmas
        }
    }
}

extern "C" void kernel_launch(void* const* d_in, const int* in_sizes, int n_in,
                              void* d_out, int out_size, void* d_ws, size_t ws_size,
                              hipStream_t stream) {
    const float* fm   = (const float*)d_in[0];
    const float* grid = (const float*)d_in[1];
    const float* xt   = (const float*)d_in[2];
    const float* lsp  = (const float*)d_in[3];
    float* out = (float*)d_out;
    float* sp  = (float*)d_ws;

    const int n_target = in_sizes[2] / 2;                 // 8192
    const size_t sp_bytes = (size_t)2 * NA * NA * sizeof(float);
    const int use_sp = (ws_size >= sp_bytes) ? 1 : 0;

    if (use_sp) {
        const int n4 = 2 * NA * NA / 4;                   // 8192 float4s
        hipLaunchKernelGGL(softplus_pre, dim3((n4 + 255) / 256), dim3(256), 0, stream,
                           fm, sp);
    }
    const int blocks = (n_target + TT - 1) / TT;          // 512
    hipLaunchKernelGGL(cnp_main, dim3(blocks), dim3(THREADS), 0, stream,
                       fm, sp, grid, xt, lsp, out, n_target, use_sp);
}

// Round 8
// 18.048 us; speedup vs baseline: 1.8781x; 1.8781x over previous
//
#include <hip/hip_runtime.h>
#include <hip/hip_bf16.h>
#include <math.h>

// Steerable CNP target prediction — separable RBF + bf16 MFMA.
//
// out[t,c] = (sum_i Kx[t,i] * V[t,c,i]) / (Sx[t]*Sy[t]),
//   V[t,c,i] = sum_j Ky[t,j] * FMc[j,i]   <- GEMM: mfma_f32_16x16x32_bf16
// Kx,Ky,Sx,Sy computed in fp32 (exact denominators); Ky/FM rounded to bf16
// for the MFMA (error averages over 128^2 kernel-weighted terms -> ~1e-4).
//
// pre-kernel: softplus(c2,c3) + fp32->bf16 + B-fragment-linear layout in ws:
//   bfB[c][n][s][L][e] = FM[c][k][i], k = s*32+(L>>4)*8+e, i = n*16+(L&15)
// main kernel per block (16 targets, 512 thr, 8 waves = channel x n-half):
//   phase 0: exps -> Kx fp32 LDS, Ky bf16 A-frag LDS, Sx/Sy wave-reduced
//   phase 1: 16 MFMAs/wave (4 n-tiles x 4 K-steps), B-frags direct from ws
//   phase 2: stage-2 dot with Kx (C/D map: col=lane&15 -> i, row=(lane>>4)*4+r -> t)

#define NA      128
#define TT      16
#define THREADS 512

typedef __attribute__((ext_vector_type(8))) short short8;
typedef __attribute__((ext_vector_type(4))) float f32x4;

__device__ __forceinline__ short f2bf(float x) {
    __hip_bfloat16 h = __float2bfloat16(x);
    return *reinterpret_cast<short*>(&h);
}

// ---------- pre-kernel: FM -> softplus'd bf16 fragment-linear layout ----------
__global__ __launch_bounds__(256)
void pack_pre(const float* __restrict__ fm, short* __restrict__ bfB)
{
    const int idx = blockIdx.x * 256 + threadIdx.x;   // (c,n,s,L): 4*8*4*64 = 8192
    if (idx >= 8192) return;
    const int L = idx & 63;
    const int s = (idx >> 6) & 3;
    const int n = (idx >> 8) & 7;
    const int c = idx >> 11;
    const int i  = n * 16 + (L & 15);
    const int k0 = s * 32 + (L >> 4) * 8;
    const float* src = fm + c * NA * NA;

    short8 o;
#pragma unroll
    for (int e = 0; e < 8; ++e) {
        float x = src[(k0 + e) * NA + i];
        if (c >= 2) x = (x > 15.0f) ? x : log1pf(__expf(x));   // softplus
        o[e] = f2bf(x);
    }
    *reinterpret_cast<short8*>(&bfB[idx * 8]) = o;
}

// ---------- main kernel ----------
__global__ __launch_bounds__(THREADS)
void cnp_mfma(const short* __restrict__ bfB,   // [4][8][4][64][8] bf16
              const float* __restrict__ grid,  // [NA*NA][2]
              const float* __restrict__ xt,    // [T][2]
              const float* __restrict__ lsp,   // [1]
              float* __restrict__ out,         // means [T][2] then sigmas [T][2]
              int n_target)
{
    __shared__ __attribute__((aligned(16))) float Kx[TT * NA];      // 8 KB
    __shared__ __attribute__((aligned(16))) short kyA[4 * 64 * 8];  // 4 KB, A-frags
    __shared__ float psx[TT][2], psy[TT][2];
    __shared__ float red[4][2][TT];

    const int tid  = threadIdx.x;
    const int wid  = tid >> 6;
    const int c    = wid & 3;         // channel
    const int nh   = wid >> 2;        // n-half (i-tiles nh*4 .. nh*4+3)
    const int lane = tid & 63;
    const int t0   = blockIdx.x * TT;

    const float l      = lsp[0];
    const float inv2l2 = 0.5f / (l * l);

    // ---- phase 0: exps -> LDS (Kx fp32, Ky bf16 A-frag) + Sx/Sy ----
    // grid[g] = (ax[g>>7], ax[g&127])  =>  ax[j] = grid[j*2+1]
#pragma unroll
    for (int s = 0; s < 4; ++s) {
        const int k = s * THREADS + tid;   // 0..2047; wave-uniform t, half
        const int t = k >> 7;
        const int j = k & 127;
        int tg = t0 + t; if (tg >= n_target) tg = n_target - 1;
        const float ax = grid[j * 2 + 1];
        const float dx = xt[tg * 2 + 0] - ax;
        const float dy = xt[tg * 2 + 1] - ax;
        const float kxv = __expf(-dx * dx * inv2l2);
        const float kyv = __expf(-dy * dy * inv2l2);
        Kx[t * NA + j] = kxv;
        // Ky -> A-fragment layout: m = t (0..15), k-pos = j
        const int ss = j >> 5, g = (j & 31) >> 3, e = j & 7;
        kyA[((ss * 64) + g * 16 + (t & 15)) * 8 + e] = f2bf(kyv);
        float sx = kxv, sy = kyv;
        sx += __shfl_xor(sx, 1);  sy += __shfl_xor(sy, 1);
        sx += __shfl_xor(sx, 2);  sy += __shfl_xor(sy, 2);
        sx += __shfl_xor(sx, 4);  sy += __shfl_xor(sy, 4);
        sx += __shfl_xor(sx, 8);  sy += __shfl_xor(sy, 8);
        sx += __shfl_xor(sx, 16); sy += __shfl_xor(sy, 16);
        sx += __shfl_xor(sx, 32); sy += __shfl_xor(sy, 32);
        if (lane == 0) {
            const int half = (k >> 6) & 1;
            psx[t][half] = sx;
            psy[t][half] = sy;
        }
    }
    __syncthreads();

    // ---- A-frags (shared by all waves) ----
    const short8* kap = reinterpret_cast<const short8*>(kyA);
    const short8 a0 = kap[0 * 64 + lane];
    const short8 a1 = kap[1 * 64 + lane];
    const short8 a2 = kap[2 * 64 + lane];
    const short8 a3 = kap[3 * 64 + lane];

    // ---- phase 1+2: 4 n-tiles, each 4 MFMAs + Kx dot ----
    const short8* bbase = reinterpret_cast<const short8*>(bfB)
                        + c * 2048 + nh * 4 * 256 + lane;   // (c*8+n)*256 + s*64 + lane
    const int icol = lane & 15;
    const int tb   = (lane >> 4) * 4;
    f32x4 p = {0.f, 0.f, 0.f, 0.f};

#pragma unroll
    for (int nn = 0; nn < 4; ++nn) {
        const short8* bp = bbase + nn * 256;
        f32x4 acc = {0.f, 0.f, 0.f, 0.f};
        acc = __builtin_amdgcn_mfma_f32_16x16x32_bf16(a0, bp[0],   acc, 0, 0, 0);
        acc = __builtin_amdgcn_mfma_f32_16x16x32_bf16(a1, bp[64],  acc, 0, 0, 0);
        acc = __builtin_amdgcn_mfma_f32_16x16x32_bf16(a2, bp[128], acc, 0, 0, 0);
        acc = __builtin_amdgcn_mfma_f32_16x16x32_bf16(a3, bp[192], acc, 0, 0, 0);
        const int i = (nh * 4 + nn) * 16 + icol;
        p.x = fmaf(Kx[(tb + 0) * NA + i], acc.x, p.x);
        p.y = fmaf(Kx[(tb + 1) * NA + i], acc.y, p.y);
        p.z = fmaf(Kx[(tb + 2) * NA + i], acc.z, p.z);
        p.w = fmaf(Kx[(tb + 3) * NA + i], acc.w, p.w);
    }

    // reduce over the 16 i-lanes (strides 1,2,4,8)
#pragma unroll
    for (int st = 1; st <= 8; st <<= 1) {
        p.x += __shfl_xor(p.x, st);
        p.y += __shfl_xor(p.y, st);
        p.z += __shfl_xor(p.z, st);
        p.w += __shfl_xor(p.w, st);
    }
    if ((lane & 15) == 0) {
        red[c][nh][tb + 0] = p.x;
        red[c][nh][tb + 1] = p.y;
        red[c][nh][tb + 2] = p.z;
        red[c][nh][tb + 3] = p.w;
    }
    __syncthreads();

    // ---- phase 3: combine n-halves, normalize, write (64 outputs) ----
    if (tid < 4 * TT) {
        const int t  = tid & (TT - 1);
        const int cc = tid >> 4;            // requires TT == 16
        const int tg = t0 + t;
        if (tg < n_target) {
            const float numer = red[cc][0][t] + red[cc][1][t];
            const float Sx = psx[t][0] + psx[t][1];
            const float Sy = psy[t][0] + psy[t][1];
            const float val = numer / (Sx * Sy);
            if (cc < 2) out[tg * 2 + cc] = val;                        // means
            else        out[n_target * 2 + tg * 2 + (cc - 2)] = val;   // sigmas
        }
    }
}

extern "C" void kernel_launch(void* const* d_in, const int* in_sizes, int n_in,
                              void* d_out, int out_size, void* d_ws, size_t ws_size,
                              hipStream_t stream) {
    const float* fm   = (const float*)d_in[0];
    const float* grid = (const float*)d_in[1];
    const float* xt   = (const float*)d_in[2];
    const float* lsp  = (const float*)d_in[3];
    float* out = (float*)d_out;
    short* bfB = (short*)d_ws;                     // 4*8*4*64*8 bf16 = 128 KB

    const int n_target = in_sizes[2] / 2;          // 8192

    hipLaunchKernelGGL(pack_pre, dim3(32), dim3(256), 0, stream, fm, bfB);

    const int blocks = (n_target + TT - 1) / TT;   // 512
    hipLaunchKernelGGL(cnp_mfma, dim3(blocks), dim3(THREADS), 0, stream,
                       bfB, grid, xt, lsp, out, n_target);
}

// Round 9
// 16.135 us; speedup vs baseline: 2.1008x; 1.1186x over previous
//
#include <hip/hip_runtime.h>
#include <hip/hip_bf16.h>
#include <math.h>

// Steerable CNP target prediction — separable RBF + bf16 MFMA.
//
// out[t,c] = (sum_i Kx[t,i] * V[t,c,i]) / (Sx[t]*Sy[t]),
//   V[t,c,i] = sum_j Ky[t,j] * FMc[j,i]   <- GEMM: mfma_f32_16x16x32_bf16
// Kx,Ky,Sx,Sy in fp32 (exact denominators); Ky/FM rounded to bf16 for MFMA.
//
// Round 9 vs round 8 (18.0us):
//  - phase 0 no longer does per-iter 6-deep dependent shuffle chains for
//    Sx/Sy; Ky also stored fp32 in LDS, one shallow post-barrier reduce
//    (32 groups x 16 lanes, 2x ds_read_b128 + 4 shuffles).
//  - pack_pre inverted: thread-per-input-float4, coalesced reads, 64 blocks.

#define NA      128
#define TT      16
#define THREADS 512

typedef __attribute__((ext_vector_type(8))) short short8;
typedef __attribute__((ext_vector_type(4))) float f32x4;

__device__ __forceinline__ short f2bf(float x) {
    __hip_bfloat16 h = __float2bfloat16(x);
    return *reinterpret_cast<short*>(&h);
}

// ---------- pre-kernel: FM -> softplus'd bf16 fragment-linear layout ----------
// bfB[(((c*8+n)*4+s)*64+L)*8+e] = FMc[k][i], k=s*32+((L>>4)&3)*8+e, i=n*16+(L&15)
__global__ __launch_bounds__(256)
void pack_pre(const float* __restrict__ fm, short* __restrict__ bfB)
{
    const int idx = blockIdx.x * 256 + threadIdx.x;   // 16384 = 4c x 128k x 32 i4
    const int c  = idx >> 12;
    const int k  = (idx >> 5) & 127;
    const int i0 = (idx & 31) * 4;

    float4 v = *reinterpret_cast<const float4*>(fm + c * NA * NA + k * NA + i0);
    if (c >= 2) {
        v.x = (v.x > 15.0f) ? v.x : log1pf(__expf(v.x));
        v.y = (v.y > 15.0f) ? v.y : log1pf(__expf(v.y));
        v.z = (v.z > 15.0f) ? v.z : log1pf(__expf(v.z));
        v.w = (v.w > 15.0f) ? v.w : log1pf(__expf(v.w));
    }
    const int s = k >> 5;
    const int e = k & 7;
    const int Lk = ((k >> 3) & 3) * 16;
    const float vv[4] = {v.x, v.y, v.z, v.w};
#pragma unroll
    for (int d = 0; d < 4; ++d) {
        const int i = i0 + d;
        const int n = i >> 4;
        const int L = Lk + (i & 15);
        bfB[(((c * 8 + n) * 4 + s) * 64 + L) * 8 + e] = f2bf(vv[d]);
    }
}

// ---------- main kernel ----------
__global__ __launch_bounds__(THREADS)
void cnp_mfma(const short* __restrict__ bfB,   // [4][8][4][64][8] bf16
              const float* __restrict__ grid,  // [NA*NA][2]
              const float* __restrict__ xt,    // [T][2]
              const float* __restrict__ lsp,   // [1]
              float* __restrict__ out,         // means [T][2] then sigmas [T][2]
              int n_target)
{
    __shared__ __attribute__((aligned(16))) float Kx[TT * NA];      // 8 KB
    __shared__ __attribute__((aligned(16))) float Ky32[TT * NA];    // 8 KB
    __shared__ __attribute__((aligned(16))) short kyA[4 * 64 * 8];  // 4 KB, A-frags
    __shared__ float psx[TT], psy[TT];
    __shared__ float red[4][2][TT];

    const int tid  = threadIdx.x;
    const int wid  = tid >> 6;
    const int c    = wid & 3;         // channel
    const int nh   = wid >> 2;        // n-half (i-tiles nh*4 .. nh*4+3)
    const int lane = tid & 63;
    const int t0   = blockIdx.x * TT;

    const float l      = lsp[0];
    const float inv2l2 = 0.5f / (l * l);

    // ---- phase 0: exps -> LDS (Kx fp32, Ky fp32 + bf16 A-frag) ----
    // grid[g] = (ax[g>>7], ax[g&127])  =>  ax[j] = grid[j*2+1]
#pragma unroll
    for (int s = 0; s < 4; ++s) {
        const int k = s * THREADS + tid;   // 0..2047
        const int t = k >> 7;
        const int j = k & 127;
        int tg = t0 + t; if (tg >= n_target) tg = n_target - 1;
        const float ax = grid[j * 2 + 1];
        const float dx = xt[tg * 2 + 0] - ax;
        const float dy = xt[tg * 2 + 1] - ax;
        const float kxv = __expf(-dx * dx * inv2l2);
        const float kyv = __expf(-dy * dy * inv2l2);
        Kx[t * NA + j]   = kxv;
        Ky32[t * NA + j] = kyv;
        // Ky -> A-fragment layout: m = t (0..15), k-pos = j
        const int ss = j >> 5, g = (j & 31) >> 3, e = j & 7;
        kyA[((ss * 64) + g * 16 + (t & 15)) * 8 + e] = f2bf(kyv);
    }
    __syncthreads();

    // ---- Sx/Sy: one shallow reduce. 32 groups (t x axis) x 16 lanes ----
    {
        const int grp  = tid >> 4;        // 0..31
        const int l16  = tid & 15;
        const int t    = grp >> 1;
        const int axis = grp & 1;
        const float* kb = axis ? Ky32 : Kx;
        const float4 q0 = *reinterpret_cast<const float4*>(&kb[t * NA + l16 * 8]);
        const float4 q1 = *reinterpret_cast<const float4*>(&kb[t * NA + l16 * 8 + 4]);
        float u = ((q0.x + q0.y) + (q0.z + q0.w)) + ((q1.x + q1.y) + (q1.z + q1.w));
        u += __shfl_xor(u, 1); u += __shfl_xor(u, 2);
        u += __shfl_xor(u, 4); u += __shfl_xor(u, 8);
        if (l16 == 0) { if (axis) psy[t] = u; else psx[t] = u; }
    }

    // ---- A-frags (shared by all waves) ----
    const short8* kap = reinterpret_cast<const short8*>(kyA);
    const short8 a0 = kap[0 * 64 + lane];
    const short8 a1 = kap[1 * 64 + lane];
    const short8 a2 = kap[2 * 64 + lane];
    const short8 a3 = kap[3 * 64 + lane];

    // ---- phase 1+2: 4 n-tiles, each 4 MFMAs + Kx dot ----
    const short8* bbase = reinterpret_cast<const short8*>(bfB)
                        + c * 2048 + nh * 4 * 256 + lane;   // (c*8+n)*256 + s*64 + L
    const int icol = lane & 15;
    const int tb   = (lane >> 4) * 4;
    f32x4 p = {0.f, 0.f, 0.f, 0.f};

#pragma unroll
    for (int nn = 0; nn < 4; ++nn) {
        const short8* bp = bbase + nn * 256;
        f32x4 acc = {0.f, 0.f, 0.f, 0.f};
        acc = __builtin_amdgcn_mfma_f32_16x16x32_bf16(a0, bp[0],   acc, 0, 0, 0);
        acc = __builtin_amdgcn_mfma_f32_16x16x32_bf16(a1, bp[64],  acc, 0, 0, 0);
        acc = __builtin_amdgcn_mfma_f32_16x16x32_bf16(a2, bp[128], acc, 0, 0, 0);
        acc = __builtin_amdgcn_mfma_f32_16x16x32_bf16(a3, bp[192], acc, 0, 0, 0);
        const int i = (nh * 4 + nn) * 16 + icol;
        p.x = fmaf(Kx[(tb + 0) * NA + i], acc.x, p.x);
        p.y = fmaf(Kx[(tb + 1) * NA + i], acc.y, p.y);
        p.z = fmaf(Kx[(tb + 2) * NA + i], acc.z, p.z);
        p.w = fmaf(Kx[(tb + 3) * NA + i], acc.w, p.w);
    }

    // reduce over the 16 i-lanes (strides 1,2,4,8)
#pragma unroll
    for (int st = 1; st <= 8; st <<= 1) {
        p.x += __shfl_xor(p.x, st);
        p.y += __shfl_xor(p.y, st);
        p.z += __shfl_xor(p.z, st);
        p.w += __shfl_xor(p.w, st);
    }
    if ((lane & 15) == 0) {
        red[c][nh][tb + 0] = p.x;
        red[c][nh][tb + 1] = p.y;
        red[c][nh][tb + 2] = p.z;
        red[c][nh][tb + 3] = p.w;
    }
    __syncthreads();

    // ---- phase 3: combine n-halves, normalize, write (64 outputs) ----
    if (tid < 4 * TT) {
        const int t  = tid & (TT - 1);
        const int cc = tid >> 4;            // requires TT == 16
        const int tg = t0 + t;
        if (tg < n_target) {
            const float numer = red[cc][0][t] + red[cc][1][t];
            const float val = numer / (psx[t] * psy[t]);
            if (cc < 2) out[tg * 2 + cc] = val;                        // means
            else        out[n_target * 2 + tg * 2 + (cc - 2)] = val;   // sigmas
        }
    }
}

extern "C" void kernel_launch(void* const* d_in, const int* in_sizes, int n_in,
                              void* d_out, int out_size, void* d_ws, size_t ws_size,
                              hipStream_t stream) {
    const float* fm   = (const float*)d_in[0];
    const float* grid = (const float*)d_in[1];
    const float* xt   = (const float*)d_in[2];
    const float* lsp  = (const float*)d_in[3];
    float* out = (float*)d_out;
    short* bfB = (short*)d_ws;                     // 4*8*4*64*8 bf16 = 128 KB

    const int n_target = in_sizes[2] / 2;          // 8192

    hipLaunchKernelGGL(pack_pre, dim3(64), dim3(256), 0, stream, fm, bfB);

    const int blocks = (n_target + TT - 1) / TT;   // 512
    hipLaunchKernelGGL(cnp_mfma, dim3(blocks), dim3(THREADS), 0, stream,
                       bfB, grid, xt, lsp, out, n_target);
}